// Round 1
// baseline (46.614 us; speedup 1.0000x reference)
//
#include <hip/hip_runtime.h>

// TopologicalLoss: loss = mean(([1,0]-target)^2); grad[b,l,c] = mask[b,l] ? (per_b[b]-loss)/eps : 0
// B=8, L=1024, C=8192. Output: [loss, grad(flat)] = 67,108,865 f32.

#define B_DIM 8
#define L_DIM 1024
#define C_DIM 8192
#define NROWS (B_DIM * L_DIM)   // 8192
#define EPS_INV 1000.0f

// Kernel 1: build per-row fill value table in ws: rowval[0..8191], rowval[8192] = loss.
__global__ void topo_prep(const void* __restrict__ mask_raw,
                          const float* __restrict__ target,
                          float* __restrict__ rowval)
{
    int r = blockIdx.x * blockDim.x + threadIdx.x;
    if (r >= NROWS) return;

    // Detect mask storage: int32 (one 0/1 per 4 bytes -> upper 3 bytes of each
    // word are zero) vs 1-byte bool (random 0/1 bytes -> some byte at offset
    // %4 != 0 is nonzero with prob 1 - 2^-96 over the first 128 bytes).
    const unsigned int* mw = (const unsigned int*)mask_raw;
    bool byte_mode = false;
#pragma unroll
    for (int i = 0; i < 32; ++i) {
        if (mw[i] & 0xFFFFFF00u) byte_mode = true;
    }

    // loss = (1/16) * sum_b [(1 - t[b][0])^2 + t[b][1]^2]
    float loss = 0.0f;
#pragma unroll
    for (int b = 0; b < B_DIM; ++b) {
        float t0 = target[2 * b];
        float t1 = target[2 * b + 1];
        float e0 = 1.0f - t0;
        loss += e0 * e0 + t1 * t1;
    }
    loss *= (1.0f / 16.0f);

    // per_b for this row's batch (recomputed to avoid runtime-indexed array -> scratch)
    int b = r >> 10;                       // r / L_DIM
    float t0 = target[2 * b];
    float t1 = target[2 * b + 1];
    float e0 = 1.0f - t0;
    float per_b = 0.5f * (e0 * e0 + t1 * t1);
    float diff = (per_b - loss) * EPS_INV;

    int mval = byte_mode ? (int)((const unsigned char*)mask_raw)[r]
                         : ((const int*)mask_raw)[r];
    rowval[r] = mval ? diff : 0.0f;
    if (r == 0) rowval[NROWS] = loss;
}

// Kernel 2: fill d_out with aligned float4 stores.
// out[0] = loss; out[1 + g] = grad[g] for g in [0, B*L*C).
// Chunk m covers out[4m .. 4m+3]:
//   m == 0: {loss, grad[0], grad[1], grad[2]}            (all row 0)
//   m >= 1: {grad[4m-1], grad[4m], grad[4m+1], grad[4m+2]}
// grad indices 4m..4m+2 are always in the same row (row = g >> 13 changes only
// at multiples of 8192, which are == 0 mod 4). grad[4m-1] may be previous row.
__global__ void topo_fill(const float* __restrict__ rowval,
                          float* __restrict__ out,
                          long long M)
{
    long long stride = (long long)gridDim.x * blockDim.x;
    for (long long m = (long long)blockIdx.x * blockDim.x + threadIdx.x;
         m < M; m += stride) {
        long long g = m << 2;                 // grad index of lane .y
        float val = rowval[g >> 13];          // row of 4m..4m+2
        float vx;
        if (m == 0) {
            vx = rowval[NROWS];               // loss
        } else if ((g & (C_DIM - 1)) == 0) {
            vx = rowval[(g - 1) >> 13];       // row boundary: 4m-1 in prev row
        } else {
            vx = val;
        }
        float4 v = make_float4(vx, val, val, val);
        *reinterpret_cast<float4*>(out + g) = v;
        if (m == M - 1) {
            out[M << 2] = rowval[NROWS - 1];  // final grad element (row 8191)
        }
    }
}

extern "C" void kernel_launch(void* const* d_in, const int* in_sizes, int n_in,
                              void* d_out, int out_size, void* d_ws, size_t ws_size,
                              hipStream_t stream) {
    // d_in[0] = logits (unused), d_in[1] = mask (8192 bool/int), d_in[2] = target (16 f32)
    const void*  mask   = d_in[1];
    const float* target = (const float*)d_in[2];
    float* rowval = (float*)d_ws;
    float* out    = (float*)d_out;

    topo_prep<<<NROWS / 256, 256, 0, stream>>>(mask, target, rowval);

    long long M = ((long long)out_size - 1) >> 2;   // 16,777,216 float4 chunks
    topo_fill<<<4096, 256, 0, stream>>>(rowval, out, M);
}